// Round 4
// baseline (2599.875 us; speedup 1.0000x reference)
//
#include <hip/hip_runtime.h>
#include <hip/hip_bf16.h>

#define NS 512
#define NB 256
#define NA 16
#define NR_ 256

typedef short s16x8 __attribute__((ext_vector_type(8)));
typedef float f32x4 __attribute__((ext_vector_type(4)));

union BU { uint4 u4; unsigned short us[8]; s16x8 v; unsigned long long ull[2]; };

__device__ __forceinline__ float bf2f(unsigned short h){
  unsigned u = ((unsigned)h) << 16;
  return __builtin_bit_cast(float, u);
}
__device__ __forceinline__ unsigned short f2bf(float f){
  unsigned u = __builtin_bit_cast(unsigned, f);
  u += 0x7fffu + ((u >> 16) & 1u);
  return (unsigned short)(u >> 16);
}
__device__ __forceinline__ float fsig(float x){ return 1.f/(1.f+__expf(-x)); }
__device__ __forceinline__ float ftanh_(float x){ float e=__expf(2.f*x); return 1.f - 2.f/(e+1.f); }

// ---- detect done_flags dtype: u8-bool vs int32 (hdr[0]=1 -> byte format) ----
__global__ void k_detect(const unsigned* __restrict__ done, unsigned* __restrict__ hdr){
  unsigned any = 0;
  for (int i = threadIdx.x; i < 32768; i += 256) any |= (done[i] > 1u) ? 1u : 0u;
  if (__ballot(any)) { if ((threadIdx.x & 63) == 0) atomicOr(hdr, 1u); }
}

__global__ void k_norm(const unsigned char* __restrict__ d8, const int* __restrict__ d32,
                       const unsigned* __restrict__ hdr, unsigned char* __restrict__ dm){
  int i = blockIdx.x*256 + threadIdx.x;
  bool u8 = (hdr[0] & 1u) != 0;
  unsigned char v;
  if (u8) v = (d8[i] != 0) ? 1 : 0; else v = (d32[i] != 0) ? 1 : 0;
  dm[i] = v;
}

// ---- w_ih -> bf16 padded (1024 x 96), bsum = b_ih + b_hh ----
__global__ void k_wbprep(const float* __restrict__ w_ih, const float* __restrict__ b_ih,
                         const float* __restrict__ b_hh, unsigned short* __restrict__ wb,
                         float* __restrict__ bsum){
  const int g = blockIdx.x*256 + threadIdx.x;
  bsum[g] = b_ih[g] + b_hh[g];
  const float* src = w_ih + (size_t)g*81;
  unsigned short* dst = wb + (size_t)g*96;
  for (int k=0;k<81;k++) dst[k]=f2bf(src[k]);
  for (int k=81;k<96;k++) dst[k]=0;
}

// ---- pack w_hh into per-lane MFMA fragment order ----
// frag (wave dw 0..7, idx 0..63) where idx = kt*8 + mt; gate=mt>>1, half=mt&1.
// chunk c = lp*16+lr (lane id), 16B: w_hh[gate*256 + dw*32 + half*16 + lr][kt*32+lp*8 .. +7] bf16.
__global__ void k_wprep2(const float* __restrict__ w_hh, unsigned short* __restrict__ wpack){
  const int G = blockIdx.x*256 + threadIdx.x;   // 0..32767
  const int dw  = G >> 12;
  const int rem = G & 4095;
  const int idx = rem >> 6;
  const int c   = rem & 63;
  const int lp = c >> 4, lr = c & 15;
  const int kt = idx >> 3, mt = idx & 7;
  const int grow = ((mt>>1)<<8) + (dw<<5) + ((mt&1)<<4) + lr;
  const int kcol = (kt<<5) + (lp<<3);
  const float* src = w_hh + (size_t)grow*256 + kcol;
  float4 a = *(const float4*)src;
  float4 b = *(const float4*)(src+4);
  BU u;
  u.us[0]=f2bf(a.x); u.us[1]=f2bf(a.y); u.us[2]=f2bf(a.z); u.us[3]=f2bf(a.w);
  u.us[4]=f2bf(b.x); u.us[5]=f2bf(b.y); u.us[6]=f2bf(b.z); u.us[7]=f2bf(b.w);
  *(uint4*)(wpack + (size_t)G*8) = u.u4;
}

// ---- activations: act[r, 0:96] = [fc(x) | reward | onehot | pad] bf16 ----
__global__ void k_act(const float* __restrict__ input, const float* __restrict__ reward,
                      const int* __restrict__ lastact, const float* __restrict__ fc_w,
                      const float* __restrict__ fc_b, unsigned short* __restrict__ act, int n0){
  __shared__ float wf[1024];
  __shared__ float bfc[64];
  const int tid = threadIdx.x;
  for (int i=tid;i<1024;i+=256) wf[i]=fc_w[i];
  if (tid<64) bfc[tid]=fc_b[tid];
  __syncthreads();
  const int r = blockIdx.x*256 + tid;
  const int n = n0 + r;
  float in[16];
  const float4* ip = (const float4*)(input + (size_t)n*16);
  #pragma unroll
  for (int i=0;i<4;i++){ float4 v=ip[i]; in[4*i]=v.x; in[4*i+1]=v.y; in[4*i+2]=v.z; in[4*i+3]=v.w; }
  unsigned short o[96];
  const float4* wf4=(const float4*)wf;
  #pragma unroll
  for (int q=0;q<64;q++){
    float a=bfc[q];
    #pragma unroll
    for (int k4=0;k4<4;k4++){
      float4 wv=wf4[q*4+k4];
      a += in[4*k4]*wv.x + in[4*k4+1]*wv.y + in[4*k4+2]*wv.z + in[4*k4+3]*wv.w;
    }
    o[q]=f2bf(a);
  }
  o[64]=f2bf(reward[n]);
  const int la = lastact[n];
  #pragma unroll
  for (int k=0;k<16;k++) o[65+k] = (k==la) ? (unsigned short)0x3F80 : (unsigned short)0;
  #pragma unroll
  for (int k=81;k<96;k++) o[k]=0;
  uint4* dst=(uint4*)(act + (size_t)r*96);
  #pragma unroll
  for (int i=0;i<12;i++){
    BU b;
    #pragma unroll
    for (int jj=0;jj<8;jj++) b.us[jj]=o[i*8+jj];
    dst[i]=b.u4;
  }
}

// ---- Xg GEMM: xg[M,1024] = act[M,96] @ wb[1024,96]^T + bsum, bf16 out ----
__launch_bounds__(256,1) __global__ void k_gemm(
    const unsigned short* __restrict__ act, const unsigned short* __restrict__ wb,
    const float* __restrict__ bsum, unsigned short* __restrict__ xg, int mtiles){
  __shared__ __align__(16) unsigned short lA[128*104];
  __shared__ __align__(16) unsigned short lB[128*104];
  const int bm = blockIdx.x % mtiles;
  const int bn = blockIdx.x / mtiles;
  const int tid = threadIdx.x;
  {
    const int r = tid >> 1, sg = tid & 1;
    const uint4* sa = (const uint4*)(act + (size_t)(bm*128 + r)*96 + sg*48);
    const uint4* sb = (const uint4*)(wb  + (size_t)(bn*128 + r)*96 + sg*48);
    uint4* da = (uint4*)&lA[r*104 + sg*48];
    uint4* db = (uint4*)&lB[r*104 + sg*48];
    #pragma unroll
    for (int i=0;i<6;i++){ da[i]=sa[i]; db[i]=sb[i]; }
  }
  __syncthreads();
  const int wid = tid >> 6, lane = tid & 63;
  const int wm = wid >> 1, wn = wid & 1;
  const int lr = lane & 15, lp = lane >> 4;
  f32x4 acc[4][4] = {};
  #pragma unroll
  for (int kt=0;kt<3;kt++){
    s16x8 af[4], bf[4];
    #pragma unroll
    for (int mi=0;mi<4;mi++)
      af[mi] = *(const s16x8*)&lA[(wm*64 + mi*16 + lr)*104 + kt*32 + lp*8];
    #pragma unroll
    for (int ni=0;ni<4;ni++)
      bf[ni] = *(const s16x8*)&lB[(wn*64 + ni*16 + lr)*104 + kt*32 + lp*8];
    #pragma unroll
    for (int mi=0;mi<4;mi++){
      #pragma unroll
      for (int ni=0;ni<4;ni++)
        acc[mi][ni] = __builtin_amdgcn_mfma_f32_16x16x32_bf16(af[mi], bf[ni], acc[mi][ni], 0,0,0);
    }
  }
  #pragma unroll
  for (int ni=0;ni<4;ni++){
    const int col = bn*128 + wn*64 + ni*16 + lr;
    const float bias = bsum[col];
    #pragma unroll
    for (int mi=0;mi<4;mi++){
      const int row = bm*128 + wm*64 + mi*16 + lp*4;
      #pragma unroll
      for (int rr=0;rr<4;rr++)
        xg[((size_t)(row+rr)<<10) + col] = f2bf(acc[mi][ni][rr] + bias);
    }
  }
}

// ---- persistent LSTM core (R4): 16 fully independent WGs, 512 thr (8 waves) ----
// WG g owns batch rows g*16..g*16+15 and the FULL w_hh: 144KB in LDS (frag idx<18
// per wave) + 46 frags x 4 VGPR in registers. h passes through an 8KB LDS buffer
// with __syncthreads only. ZERO cross-WG communication.
__launch_bounds__(512,1) __global__ void k_main(
    const float* __restrict__ hidden, const unsigned short* __restrict__ xg,
    const unsigned char* __restrict__ dm, const unsigned short* __restrict__ wpack,
    unsigned short* __restrict__ hs, float* __restrict__ cstate, int t0, int CH){
  __shared__ __align__(16) unsigned short LW[73728];  // 144KB: [wave][idx 0..17][1KB frag]
  __shared__ __align__(16) unsigned short HB[4096];   // 8KB: h buffer [kt][lane*16B]
  const int tid = threadIdx.x;
  const int wg = blockIdx.x;
  const int w  = tid >> 6;
  const int lane = tid & 63;
  const int lr = lane & 15, lp = lane >> 4;
  const int bglob = (wg << 4) + lr;

  // stage LDS weights: frag idx 0..17 of each wave, linear copy (pre-packed)
  for (int it = tid; it < 9216; it += 512){
    int dw = it / 1152;                 // 1152 = 18 frags * 64 chunks
    int rem = it - dw*1152;
    *(uint4*)&LW[(size_t)dw*9216 + (size_t)rem*8] =
      *(const uint4*)(wpack + (size_t)dw*32768 + (size_t)rem*8);
  }
  // register-resident frags: idx 18..63 of this wave
  s16x8 wr[46];
  #pragma unroll
  for (int f=0; f<46; ++f)
    wr[f] = *(const s16x8*)(wpack + ((size_t)(w*64 + 18 + f) << 9) + lane*8);

  // h init into HB: thread -> chunk (kt=w, lp, lr)
  {
    const int k0 = (w<<5) + (lp<<3);
    BU u;
    if (t0 == 0){
      const float* src = hidden + (size_t)bglob*256 + k0;
      float4 a = *(const float4*)src, b = *(const float4*)(src+4);
      u.us[0]=f2bf(a.x); u.us[1]=f2bf(a.y); u.us[2]=f2bf(a.z); u.us[3]=f2bf(a.w);
      u.us[4]=f2bf(b.x); u.us[5]=f2bf(b.y); u.us[6]=f2bf(b.z); u.us[7]=f2bf(b.w);
    } else {
      u.u4 = *(const uint4*)(hs + ((size_t)((CH-1)*NB + bglob) << 8) + k0);
    }
    *(uint4*)&HB[(w<<9) + ((lp<<4)+lr)*8] = u.u4;
  }
  // c init: lane's 8 c values: b=bglob, r = w*32 + half*16 + lp*4 + rr
  float cst[8];
  {
    const float* csrc = (t0 == 0) ? (hidden + 65536) : cstate;
    #pragma unroll
    for (int half=0; half<2; ++half){
      float4 cv = *(const float4*)(csrc + (size_t)bglob*256 + (w<<5) + (half<<4) + (lp<<2));
      cst[half*4+0]=cv.x; cst[half*4+1]=cv.y; cst[half*4+2]=cv.z; cst[half*4+3]=cv.w;
    }
  }
  // xg prefetch for s=0, done mask for t0
  ushort4 xs[8];
  #pragma unroll
  for (int mt=0;mt<8;mt++)
    xs[mt] = *(const ushort4*)(xg + ((size_t)bglob<<10) + ((mt>>1)<<8) + (w<<5) + ((mt&1)<<4) + (lp<<2));
  bool dnc = dm[t0*NB + bglob] != 0;
  __syncthreads();

  for (int s = 0; s < CH; ++s){
    // acc init from staged xg (bias already folded in by k_gemm)
    f32x4 acc[8];
    #pragma unroll
    for (int mt=0;mt<8;mt++){
      acc[mt][0]=bf2f(xs[mt].x); acc[mt][1]=bf2f(xs[mt].y);
      acc[mt][2]=bf2f(xs[mt].z); acc[mt][3]=bf2f(xs[mt].w);
    }
    // prefetch next step's xg + done (clamped; hidden under MFMA phase)
    const int sn = (s+1 < CH) ? (s+1) : s;
    #pragma unroll
    for (int mt=0;mt<8;mt++)
      xs[mt] = *(const ushort4*)(xg + ((size_t)(sn*NB + bglob)<<10) + ((mt>>1)<<8) + (w<<5) + ((mt&1)<<4) + (lp<<2));
    const bool dnn = dm[(t0+sn)*NB + bglob] != 0;

    // MFMA: gates[m][b] += sum_k w[m][k] h[b][k]
    #pragma unroll
    for (int kt=0;kt<8;kt++){
      BU bu; bu.u4 = *(const uint4*)&HB[(kt<<9) + lane*8];
      if (dnc) bu.u4 = make_uint4(0,0,0,0);
      #pragma unroll
      for (int mt=0;mt<8;mt++){
        const int idx = kt*8 + mt;
        s16x8 a;
        if (idx < 18) a = *(const s16x8*)&LW[w*9216 + idx*512 + lane*8];
        else          a = wr[idx-18];
        acc[mt] = __builtin_amdgcn_mfma_f32_16x16x32_bf16(a, bu.v, acc[mt], 0,0,0);
      }
    }

    // epilogue: lane holds all 4 gates for (b=bglob, r = w*32+half*16+lp*4+rr)
    unsigned short hu[8];
    #pragma unroll
    for (int half=0; half<2; ++half){
      #pragma unroll
      for (int rr=0;rr<4;rr++){
        float cp = dnc ? 0.f : cst[half*4+rr];
        float ii = fsig(acc[0+half][rr]);
        float ff = fsig(acc[2+half][rr]);
        float g2 = ftanh_(acc[4+half][rr]);
        float oo = fsig(acc[6+half][rr]);
        float cn = ff*cp + ii*g2;
        cst[half*4+rr] = cn;
        hu[half*4+rr] = f2bf(oo*ftanh_(cn));
      }
    }
    __syncthreads();   // all waves done reading h(t-1) from HB
    #pragma unroll
    for (int half=0; half<2; ++half){
      unsigned long long hp = (unsigned long long)hu[half*4+0]
                            | ((unsigned long long)hu[half*4+1]<<16)
                            | ((unsigned long long)hu[half*4+2]<<32)
                            | ((unsigned long long)hu[half*4+3]<<48);
      // LDS: chunk (kt=w, slot=half*2+(lp>>1), lr), 8B half (lp&1)
      *(unsigned long long*)&HB[(w<<9) + ((((half<<1)+(lp>>1))<<4) + lr)*8 + ((lp&1)<<2)] = hp;
      // global hs[s][b][r0..r0+3]
      *(unsigned long long*)(hs + ((size_t)(s*NB + bglob) << 8) + (w<<5) + (half<<4) + (lp<<2)) = hp;
    }
    dnc = dnn;
    __syncthreads();   // h(t) ready in HB
  }
  // c carry
  #pragma unroll
  for (int half=0; half<2; ++half)
    *(float4*)(cstate + (size_t)bglob*256 + (w<<5) + (half<<4) + (lp<<2)) =
      make_float4(cst[half*4+0], cst[half*4+1], cst[half*4+2], cst[half*4+3]);
}

// ---- heads: logits = hs@actor_w.T + b ; values = hs@critic_w.T + b ----
__launch_bounds__(64,1) __global__ void k_proj(
    const unsigned short* __restrict__ hs, const float* __restrict__ actor_w,
    const float* __restrict__ actor_b, const float* __restrict__ critic_w,
    const float* __restrict__ critic_b, float* __restrict__ outL, float* __restrict__ outV){
  const int lane = threadIdx.x;
  const int m0 = blockIdx.x * 64;
  const int lr = lane & 15, lp = lane >> 4;
  f32x4 acc[4] = {};
  float part[4] = {0.f,0.f,0.f,0.f};
  #pragma unroll
  for (int kt=0;kt<8;kt++){
    BU bw;
    const float4* ap = (const float4*)(actor_w + (size_t)lr*256 + (kt<<5) + (lp<<3));
    float4 w0=ap[0], w1=ap[1];
    bw.us[0]=f2bf(w0.x); bw.us[1]=f2bf(w0.y); bw.us[2]=f2bf(w0.z); bw.us[3]=f2bf(w0.w);
    bw.us[4]=f2bf(w1.x); bw.us[5]=f2bf(w1.y); bw.us[6]=f2bf(w1.z); bw.us[7]=f2bf(w1.w);
    const float4* cp4 = (const float4*)(critic_w + (kt<<5) + (lp<<3));
    float4 cw0=cp4[0], cw1=cp4[1];
    #pragma unroll
    for (int mi=0;mi<4;mi++){
      BU hv; hv.u4 = *(const uint4*)(hs + ((size_t)(m0 + mi*16 + lr) << 8) + (kt<<5) + (lp<<3));
      acc[mi] = __builtin_amdgcn_mfma_f32_16x16x32_bf16(hv.v, bw.v, acc[mi], 0,0,0);
      part[mi] += bf2f(hv.us[0])*cw0.x + bf2f(hv.us[1])*cw0.y + bf2f(hv.us[2])*cw0.z + bf2f(hv.us[3])*cw0.w
                + bf2f(hv.us[4])*cw1.x + bf2f(hv.us[5])*cw1.y + bf2f(hv.us[6])*cw1.z + bf2f(hv.us[7])*cw1.w;
    }
  }
  const float ab = actor_b[lr];
  #pragma unroll
  for (int mi=0;mi<4;mi++){
    #pragma unroll
    for (int rr=0;rr<4;rr++)
      outL[(size_t)(m0 + mi*16 + lp*4 + rr)*16 + lr] = acc[mi][rr] + ab;
  }
  const float cb = critic_b[0];
  #pragma unroll
  for (int mi=0;mi<4;mi++){
    float v = part[mi];
    v += __shfl_xor(v, 16, 64);
    v += __shfl_xor(v, 32, 64);
    if (lp == 0) outV[m0 + mi*16 + lr] = v + cb;
  }
}

extern "C" void kernel_launch(void* const* d_in, const int* in_sizes, int n_in,
                              void* d_out, int out_size, void* d_ws, size_t ws_size,
                              hipStream_t stream) {
  (void)in_sizes; (void)n_in; (void)out_size;
  const float* input    = (const float*)d_in[0];
  const int*   lastact  = (const int*)d_in[1];
  const float* reward   = (const float*)d_in[2];
  const void*  done     = d_in[3];
  const float* hidden   = (const float*)d_in[4];
  const float* fc_w     = (const float*)d_in[5];
  const float* fc_b     = (const float*)d_in[6];
  const float* w_ih     = (const float*)d_in[7];
  const float* w_hh     = (const float*)d_in[8];
  const float* b_ih     = (const float*)d_in[9];
  const float* b_hh     = (const float*)d_in[10];
  const float* actor_w  = (const float*)d_in[11];
  const float* actor_b  = (const float*)d_in[12];
  const float* critic_w = (const float*)d_in[13];
  const float* critic_b = (const float*)d_in[14];
  float* outL = (float*)d_out;
  float* outV = outL + (size_t)NS*NA*NB;

  char* p = (char*)d_ws;
  unsigned*       hdr    = (unsigned*)p;                           // 256B
  unsigned char*  dmb    = (unsigned char*)(p + 1024);             // 131072
  unsigned short* wb     = (unsigned short*)(p + 132096);          // 196608
  float*          bsum   = (float*)(p + 328704);                   // 4096
  float*          cstate = (float*)(p + 332800);                   // 262144
  unsigned short* wpack  = (unsigned short*)(p + 594944);          // 524288
  const size_t fixed = 1119232;
  int CH = 256;
  while (CH > 4){
    size_t need = fixed + (size_t)CH*49152 + (size_t)CH*524288 + (size_t)CH*131072;
    if (need <= ws_size) break;
    CH >>= 1;
  }
  unsigned short* act = (unsigned short*)(p + fixed);
  unsigned short* xg  = (unsigned short*)(p + fixed + (size_t)CH*49152);
  unsigned short* hs  = (unsigned short*)(p + fixed + (size_t)CH*49152 + (size_t)CH*524288);

  hipMemsetAsync(d_ws, 0, 1024, stream);
  hipLaunchKernelGGL(k_detect, dim3(1), dim3(256), 0, stream, (const unsigned*)done, hdr);
  hipLaunchKernelGGL(k_norm, dim3(512), dim3(256), 0, stream,
                     (const unsigned char*)done, (const int*)done, hdr, dmb);
  hipLaunchKernelGGL(k_wbprep, dim3(4), dim3(256), 0, stream, w_ih, b_ih, b_hh, wb, bsum);
  hipLaunchKernelGGL(k_wprep2, dim3(128), dim3(256), 0, stream, w_hh, wpack);

  const int NC = NS / CH;
  for (int c = 0; c < NC; ++c){
    const int t0 = c * CH;
    hipLaunchKernelGGL(k_act, dim3(CH), dim3(256), 0, stream,
                       input, reward, lastact, fc_w, fc_b, act, t0*NB);
    hipLaunchKernelGGL(k_gemm, dim3(CH*2*8), dim3(256), 0, stream, act, wb, bsum, xg, CH*2);
    hipLaunchKernelGGL(k_main, dim3(16), dim3(512), 0, stream,
                       hidden, xg, dmb, wpack, hs, cstate, t0, CH);
    hipLaunchKernelGGL(k_proj, dim3(CH*4), dim3(64), 0, stream,
                       hs, actor_w, actor_b, critic_w, critic_b,
                       outL + (size_t)t0*NB*NA, outV + (size_t)t0*NB);
  }
}